// Round 4
// baseline (10290.855 us; speedup 1.0000x reference)
//
#include <hip/hip_runtime.h>
#include <hip/hip_bf16.h>

#define NB 8
#define LSEQ 2048
#define DM 768
#define DI 1536
#define DS 16
#define NT (NB*LSEQ)   // 16384 tokens

typedef __hip_bfloat16 bf16;

__device__ __forceinline__ float b2f(bf16 v){ return __bfloat162float(v); }
__device__ __forceinline__ bf16  f2b(float v){ return __float2bfloat16(v); }
__device__ __forceinline__ float silu(float v){ return v/(1.f+expf(-v)); }

// ---------------- LN stats: one wave per token ----------------
// stats[2t] = mean, stats[2t+1] = rstd
__global__ void ln_stats(const float* __restrict__ x, float* __restrict__ stats){
  int wv = threadIdx.x>>6, ln = threadIdx.x&63;
  int t = blockIdx.x*4 + wv;
  const float* xr = x + (size_t)t*DM;
  float s=0.f, s2=0.f;
  for (int i=ln;i<DM;i+=64){ float v=xr[i]; s+=v; s2+=v*v; }
  #pragma unroll
  for (int o=32;o>0;o>>=1){ s+=__shfl_down(s,o); s2+=__shfl_down(s2,o); }
  if (ln==0){
    float mean = s/(float)DM;
    stats[2*t]   = mean;
    stats[2*t+1] = rsqrtf(s2/(float)DM - mean*mean + 1e-5f);
  }
}

// ---------------- in_proj GEMM with LN fused ----------------
// xb[NT,DI], z[NT,DI] (both bf16) = LN(x)[NT,768] @ W[3072,768]^T split in half.
// grid (3072/16, NT/16), block (16,16)
__global__ void gemm_in_fused(const float* __restrict__ x, const float* __restrict__ stats,
                              const float* __restrict__ g, const float* __restrict__ bb,
                              const float* __restrict__ W,
                              bf16* __restrict__ xb, bf16* __restrict__ z){
  __shared__ float sA[16][17], sW[16][17];
  int tx=threadIdx.x, ty=threadIdx.y;
  int row  = blockIdx.y*16 + ty;
  int col0 = blockIdx.x*16;
  float mean = stats[2*row], rstd = stats[2*row+1];
  float acc=0.f;
  for (int k0=0;k0<DM;k0+=16){
    int k = k0+tx;
    sA[ty][tx] = (x[(size_t)row*DM + k]-mean)*rstd*g[k] + bb[k];
    sW[ty][tx] = W[(size_t)(col0+ty)*DM + k];
    __syncthreads();
    #pragma unroll
    for (int kk=0;kk<16;kk++) acc += sA[ty][kk]*sW[tx][kk];
    __syncthreads();
  }
  int col = col0 + tx;
  if (col < DI) xb[(size_t)row*DI + col]        = f2b(acc);
  else          z [(size_t)row*DI + col - DI]   = f2b(acc);
}

// ---------------- x_proj with conv+SiLU fused ----------------
// one block (64 threads) per token t: conv'd row in fp32 in LDS, then
// xp[t,j] = row . Wx[j]  for j<33
__global__ void xproj_conv(const bf16* __restrict__ xb, const float* __restrict__ cw,
                           const float* __restrict__ cb, const float* __restrict__ Wx,
                           float* __restrict__ xp){
  __shared__ float row[DI];
  int t = blockIdx.x;
  int l = t % LSEQ;
  const bf16* x0 = xb + (size_t)t*DI;
  for (int i=threadIdx.x;i<DI;i+=64){
    float acc = cb[i];
    acc += b2f(x0[i]) * cw[i*4+3];
    if (l>=1) acc += b2f(x0[i-(size_t)DI  ]) * cw[i*4+2];
    if (l>=2) acc += b2f(x0[i-(size_t)2*DI]) * cw[i*4+1];
    if (l>=3) acc += b2f(x0[i-(size_t)3*DI]) * cw[i*4+0];
    row[i] = silu(acc);
  }
  __syncthreads();
  int j = threadIdx.x;
  if (j < 2*DS+1){
    const float* wr = Wx + (size_t)j*DI;
    float acc=0.f;
    for (int k=0;k<DI;k++) acc += row[k]*wr[k];
    xp[(size_t)t*(2*DS+1) + j] = acc;
  }
}

// ---------------- selective scan with conv fused; gated ys overwrites xb ----------------
// grid (DI/256, NB), block 256. Per thread: channel d of batch b.
__global__ void scan_fused(const float* __restrict__ xp, const bf16* __restrict__ z,
                           const float* __restrict__ cw, const float* __restrict__ cb,
                           const float* __restrict__ dt_w, const float* __restrict__ dt_b,
                           const float* __restrict__ A_log, const float* __restrict__ Dp,
                           bf16* __restrict__ xb /* in: xb, out: gated ys */){
  int d = blockIdx.x*256 + threadIdx.x;
  int b = blockIdx.y;
  float A[DS];
  #pragma unroll
  for (int n=0;n<DS;n++) A[n] = -expf(A_log[(size_t)d*DS+n]);
  float dtw = dt_w[d], dtb = dt_b[d], Dd = Dp[d];
  float w0=cw[d*4+0], w1=cw[d*4+1], w2=cw[d*4+2], w3=cw[d*4+3];
  float cbd=cb[d];
  float f0=0.f, f1=0.f, f2=0.f;   // raw xb at t-3, t-2, t-1
  float h[DS];
  #pragma unroll
  for (int n=0;n<DS;n++) h[n]=0.f;
  __shared__ float sxp[2*DS+1];
  for (int l=0;l<LSEQ;l++){
    size_t t = (size_t)b*LSEQ + l;
    if (threadIdx.x < 2*DS+1) sxp[threadIdx.x] = xp[t*(2*DS+1)+threadIdx.x];
    __syncthreads();
    float xraw = b2f(xb[t*DI + d]);
    float c = cbd + w0*f0 + w1*f1 + w2*f2 + w3*xraw;
    float xt = silu(c);
    float zv = b2f(z[t*DI + d]);
    float dl = sxp[0]*dtw + dtb;
    float delta = (dl > 20.f) ? dl : log1pf(expf(dl));
    float dx = delta*xt;
    float y=0.f;
    #pragma unroll
    for (int n=0;n<DS;n++){
      float dA = expf(delta*A[n]);
      h[n] = dA*h[n] + dx*sxp[1+n];
      y += h[n]*sxp[1+DS+n];
    }
    y += Dd*xt;
    xb[t*DI + d] = f2b(y*silu(zv));
    f0=f1; f1=f2; f2=xraw;
    __syncthreads();
  }
}

// ---------------- out_proj GEMM + residual, fp32 store ----------------
// out[NT,768] = ys[NT,1536] @ Wo[768,1536]^T + x
__global__ void gemm_out_res(const bf16* __restrict__ A, const float* __restrict__ W,
                             const float* __restrict__ xres, float* __restrict__ out){
  __shared__ float sA[16][17], sW[16][17];
  int tx=threadIdx.x, ty=threadIdx.y;
  int row  = blockIdx.y*16 + ty;
  int col0 = blockIdx.x*16;
  float acc=0.f;
  for (int k0=0;k0<DI;k0+=16){
    sA[ty][tx] = b2f(A[(size_t)row*DI + k0 + tx]);
    sW[ty][tx] = W[(size_t)(col0+ty)*DI + k0 + tx];
    __syncthreads();
    #pragma unroll
    for (int k=0;k<16;k++) acc += sA[ty][k]*sW[tx][k];
    __syncthreads();
  }
  int col = col0 + tx;
  acc += xres[(size_t)row*DM + col];
  out[(size_t)row*DM + col] = acc;
}

extern "C" void kernel_launch(void* const* d_in, const int* in_sizes, int n_in,
                              void* d_out, int out_size, void* d_ws, size_t ws_size,
                              hipStream_t stream) {
  const float* x        = (const float*)d_in[0];
  const float* ln_g     = (const float*)d_in[1];
  const float* ln_b     = (const float*)d_in[2];
  const float* in_w     = (const float*)d_in[3];
  const float* conv_w   = (const float*)d_in[4];
  const float* conv_b   = (const float*)d_in[5];
  const float* xproj_w  = (const float*)d_in[6];
  const float* dt_w     = (const float*)d_in[7];
  const float* dt_b     = (const float*)d_in[8];
  const float* A_log    = (const float*)d_in[9];
  const float* Dp       = (const float*)d_in[10];
  const float* out_w    = (const float*)d_in[11];
  float* out = (float*)d_out;   // reference output dtype is float32

  // workspace layout (~103 MB, proven mapped in round 2):
  //   stats : NT*2 fp32           (128 KB)
  //   xp    : NT*33 fp32          (2.2 MB)
  //   xb    : NT*DI bf16          (50.3 MB)  -> becomes gated ys in place
  //   z     : NT*DI bf16          (50.3 MB)
  float* stats = (float*)d_ws;
  float* xp    = stats + (size_t)NT*2;
  bf16*  xbuf  = (bf16*)(xp + (size_t)NT*(2*DS+1));
  bf16*  zbuf  = xbuf + (size_t)NT*DI;

  ln_stats<<<NT/4, 256, 0, stream>>>(x, stats);

  gemm_in_fused<<<dim3(2*DI/16, NT/16), dim3(16,16), 0, stream>>>(
      x, stats, ln_g, ln_b, in_w, xbuf, zbuf);

  xproj_conv<<<NT, 64, 0, stream>>>(xbuf, conv_w, conv_b, xproj_w, xp);

  scan_fused<<<dim3(DI/256, NB), 256, 0, stream>>>(
      xp, zbuf, conv_w, conv_b, dt_w, dt_b, A_log, Dp, xbuf);

  gemm_out_res<<<dim3(DM/16, NT/16), dim3(16,16), 0, stream>>>(xbuf, out_w, x, out);
}

// Round 5
// 2808.929 us; speedup vs baseline: 3.6636x; 3.6636x over previous
//
#include <hip/hip_runtime.h>
#include <hip/hip_bf16.h>

#define NB 8
#define LSEQ 2048
#define DM 768
#define DI 1536
#define DS 16
#define NT (NB*LSEQ)   // 16384 tokens

typedef __hip_bfloat16 bf16;
typedef __bf16 bf16x8 __attribute__((ext_vector_type(8)));
typedef float  f32x4  __attribute__((ext_vector_type(4)));

__device__ __forceinline__ float b2f(bf16 v){ return __bfloat162float(v); }
__device__ __forceinline__ bf16  f2b(float v){ return __float2bfloat16(v); }
__device__ __forceinline__ float silu(float v){ return v/(1.f+__expf(-v)); }

// ---------------- LN stats: one wave per token ----------------
__global__ void ln_stats(const float* __restrict__ x, float* __restrict__ stats){
  int wv = threadIdx.x>>6, ln = threadIdx.x&63;
  int t = blockIdx.x*4 + wv;
  const float* xr = x + (size_t)t*DM;
  float s=0.f, s2=0.f;
  for (int i=ln;i<DM;i+=64){ float v=xr[i]; s+=v; s2+=v*v; }
  #pragma unroll
  for (int o=32;o>0;o>>=1){ s+=__shfl_down(s,o); s2+=__shfl_down(s2,o); }
  if (ln==0){
    float mean = s/(float)DM;
    stats[2*t]   = mean;
    stats[2*t+1] = rsqrtf(s2/(float)DM - mean*mean + 1e-5f);
  }
}

// ---------------- in_proj MFMA GEMM with LN fused ----------------
// xb/z bf16 [NT,DI] = LN(x)[NT,768] @ W[3072,768]^T, split at col 1536.
// grid (3072/128=24, NT/128=128), block 256 (4 waves, 2x2 of 64x64).
__global__ __launch_bounds__(256) void gemm_in_mfma(
    const float* __restrict__ x, const float* __restrict__ stats,
    const float* __restrict__ g, const float* __restrict__ bb,
    const float* __restrict__ W,
    bf16* __restrict__ xb, bf16* __restrict__ z){
  __shared__ __align__(16) bf16 sA[128][40];   // pad +8 bf16: stride 80B = 5x16B
  __shared__ __align__(16) bf16 sW[128][40];
  int tid = threadIdx.x;
  int m0 = blockIdx.y*128, n0 = blockIdx.x*128;
  int sr = tid>>1, sc = (tid&1)*16;
  int arow = m0 + sr;
  float mean = stats[2*arow], rstd = stats[2*arow+1];
  int wave = tid>>6, lane = tid&63;
  int wm = (wave>>1)*64, wn = (wave&1)*64;
  int lr = lane&15, kq = lane>>4;
  f32x4 acc[4][4];
  #pragma unroll
  for (int i=0;i<4;i++)
    #pragma unroll
    for (int j=0;j<4;j++) acc[i][j] = (f32x4){0.f,0.f,0.f,0.f};

  for (int k0=0;k0<DM;k0+=32){
    const float4* xs   = (const float4*)(x  + (size_t)arow*DM + k0 + sc);
    const float4* gs   = (const float4*)(g  + k0 + sc);
    const float4* bs   = (const float4*)(bb + k0 + sc);
    const float4* wsrc = (const float4*)(W  + (size_t)(n0+sr)*DM + k0 + sc);
    bf16 ta[16] __attribute__((aligned(16)));
    bf16 tw[16] __attribute__((aligned(16)));
    #pragma unroll
    for (int u=0;u<4;u++){
      float4 xv=xs[u], gv=gs[u], bv=bs[u], wv=wsrc[u];
      ta[4*u+0]=f2b((xv.x-mean)*rstd*gv.x+bv.x);
      ta[4*u+1]=f2b((xv.y-mean)*rstd*gv.y+bv.y);
      ta[4*u+2]=f2b((xv.z-mean)*rstd*gv.z+bv.z);
      ta[4*u+3]=f2b((xv.w-mean)*rstd*gv.w+bv.w);
      tw[4*u+0]=f2b(wv.x); tw[4*u+1]=f2b(wv.y);
      tw[4*u+2]=f2b(wv.z); tw[4*u+3]=f2b(wv.w);
    }
    *(uint4*)&sA[sr][sc]   = ((uint4*)ta)[0];
    *(uint4*)&sA[sr][sc+8] = ((uint4*)ta)[1];
    *(uint4*)&sW[sr][sc]   = ((uint4*)tw)[0];
    *(uint4*)&sW[sr][sc+8] = ((uint4*)tw)[1];
    __syncthreads();
    bf16x8 af[4], bfr[4];
    #pragma unroll
    for (int i=0;i<4;i++) af[i]  = *(const bf16x8*)&sA[wm+i*16+lr][kq*8];
    #pragma unroll
    for (int j=0;j<4;j++) bfr[j] = *(const bf16x8*)&sW[wn+j*16+lr][kq*8];
    #pragma unroll
    for (int i=0;i<4;i++)
      #pragma unroll
      for (int j=0;j<4;j++)
        acc[i][j] = __builtin_amdgcn_mfma_f32_16x16x32_bf16(af[i], bfr[j], acc[i][j], 0,0,0);
    __syncthreads();
  }
  #pragma unroll
  for (int i=0;i<4;i++){
    #pragma unroll
    for (int j=0;j<4;j++){
      int colg = n0 + wn + j*16 + lr;
      #pragma unroll
      for (int r=0;r<4;r++){
        int rowg = m0 + wm + i*16 + kq*4 + r;
        float v = acc[i][j][r];
        if (colg < DI) xb[(size_t)rowg*DI + colg]      = f2b(v);
        else           z [(size_t)rowg*DI + colg - DI] = f2b(v);
      }
    }
  }
}

// ---------------- out_proj MFMA GEMM + residual, fp32 out ----------------
// out[NT,768] = ys[NT,1536](bf16) @ Wo[768,1536]^T + xres
// grid (768/128=6, NT/128=128), block 256.
__global__ __launch_bounds__(256) void gemm_out_mfma(
    const bf16* __restrict__ ys, const float* __restrict__ W,
    const float* __restrict__ xres, float* __restrict__ out){
  __shared__ __align__(16) bf16 sA[128][40];
  __shared__ __align__(16) bf16 sW[128][40];
  int tid = threadIdx.x;
  int m0 = blockIdx.y*128, n0 = blockIdx.x*128;
  int sr = tid>>1, sc = (tid&1)*16;
  int wave = tid>>6, lane = tid&63;
  int wm = (wave>>1)*64, wn = (wave&1)*64;
  int lr = lane&15, kq = lane>>4;
  f32x4 acc[4][4];
  #pragma unroll
  for (int i=0;i<4;i++)
    #pragma unroll
    for (int j=0;j<4;j++) acc[i][j] = (f32x4){0.f,0.f,0.f,0.f};

  for (int k0=0;k0<DI;k0+=32){
    const uint4* asrc = (const uint4*)(ys + (size_t)(m0+sr)*DI + k0 + sc);
    uint4 a0 = asrc[0], a1 = asrc[1];
    const float4* wsrc = (const float4*)(W + (size_t)(n0+sr)*DI + k0 + sc);
    bf16 tw[16] __attribute__((aligned(16)));
    #pragma unroll
    for (int u=0;u<4;u++){
      float4 wv=wsrc[u];
      tw[4*u+0]=f2b(wv.x); tw[4*u+1]=f2b(wv.y);
      tw[4*u+2]=f2b(wv.z); tw[4*u+3]=f2b(wv.w);
    }
    *(uint4*)&sA[sr][sc]   = a0;
    *(uint4*)&sA[sr][sc+8] = a1;
    *(uint4*)&sW[sr][sc]   = ((uint4*)tw)[0];
    *(uint4*)&sW[sr][sc+8] = ((uint4*)tw)[1];
    __syncthreads();
    bf16x8 af[4], bfr[4];
    #pragma unroll
    for (int i=0;i<4;i++) af[i]  = *(const bf16x8*)&sA[wm+i*16+lr][kq*8];
    #pragma unroll
    for (int j=0;j<4;j++) bfr[j] = *(const bf16x8*)&sW[wn+j*16+lr][kq*8];
    #pragma unroll
    for (int i=0;i<4;i++)
      #pragma unroll
      for (int j=0;j<4;j++)
        acc[i][j] = __builtin_amdgcn_mfma_f32_16x16x32_bf16(af[i], bfr[j], acc[i][j], 0,0,0);
    __syncthreads();
  }
  #pragma unroll
  for (int i=0;i<4;i++){
    #pragma unroll
    for (int j=0;j<4;j++){
      int colg = n0 + wn + j*16 + lr;
      #pragma unroll
      for (int r=0;r<4;r++){
        int rowg = m0 + wm + i*16 + kq*4 + r;
        out[(size_t)rowg*DM + colg] = acc[i][j][r] + xres[(size_t)rowg*DM + colg];
      }
    }
  }
}

// ---------------- x_proj with conv+SiLU fused (float4) ----------------
__global__ __launch_bounds__(64) void xproj_conv(const bf16* __restrict__ xbuf,
                           const float* __restrict__ cw,
                           const float* __restrict__ cb, const float* __restrict__ Wx,
                           float* __restrict__ xp){
  __shared__ __align__(16) float row[DI];
  int t = blockIdx.x;
  int l = t % LSEQ;
  const bf16* x0 = xbuf + (size_t)t*DI;
  for (int i=threadIdx.x;i<DI;i+=64){
    float acc = cb[i];
    acc += b2f(x0[i]) * cw[i*4+3];
    if (l>=1) acc += b2f(x0[i-(size_t)DI  ]) * cw[i*4+2];
    if (l>=2) acc += b2f(x0[i-(size_t)2*DI]) * cw[i*4+1];
    if (l>=3) acc += b2f(x0[i-(size_t)3*DI]) * cw[i*4+0];
    row[i] = silu(acc);
  }
  __syncthreads();
  int j = threadIdx.x;
  if (j < 2*DS+1){
    const float4* wr = (const float4*)(Wx + (size_t)j*DI);
    const float4* rw = (const float4*)row;
    float acc=0.f;
    #pragma unroll 4
    for (int k=0;k<DI/4;k++){
      float4 a=rw[k], w=wr[k];
      acc += a.x*w.x + a.y*w.y + a.z*w.z + a.w*w.w;
    }
    xp[(size_t)t*(2*DS+1) + j] = acc;
  }
}

// ---------------- selective scan v2: 64-ch blocks, chunked xp, pipelined loads ----------------
#define SCH 64
__global__ __launch_bounds__(64) void scan_fused(
    const float* __restrict__ xp, const bf16* __restrict__ z,
    const float* __restrict__ cw, const float* __restrict__ cb,
    const float* __restrict__ dt_w, const float* __restrict__ dt_b,
    const float* __restrict__ A_log, const float* __restrict__ Dp,
    bf16* __restrict__ xb /* in: xb, out: gated ys */){
  int tid = threadIdx.x;
  int d = blockIdx.x*64 + tid;
  int b = blockIdx.y;
  float A[DS];
  #pragma unroll
  for (int n=0;n<DS;n++) A[n] = -expf(A_log[(size_t)d*DS+n]);
  float dtw = dt_w[d], dtb = dt_b[d], Dd = Dp[d];
  float w0=cw[d*4+0], w1=cw[d*4+1], w2=cw[d*4+2], w3=cw[d*4+3];
  float cbd=cb[d];
  float f0=0.f, f1=0.f, f2=0.f;
  float h[DS];
  #pragma unroll
  for (int n=0;n<DS;n++) h[n]=0.f;
  __shared__ float sxp[2][SCH*(2*DS+1)];
  const float* xpb = xp + (size_t)b*LSEQ*(2*DS+1);
  for (int i=tid;i<SCH*(2*DS+1);i+=64) sxp[0][i] = xpb[i];
  size_t tbase = (size_t)b*LSEQ;
  float xb_n = b2f(xb[tbase*DI + d]);
  float z_n  = b2f(z [tbase*DI + d]);
  __syncthreads();
  const int NCH = LSEQ/SCH;
  for (int c=0;c<NCH;c++){
    int buf = c&1;
    if (c+1 < NCH){
      const float* src = xpb + (size_t)(c+1)*SCH*(2*DS+1);
      for (int i=tid;i<SCH*(2*DS+1);i+=64) sxp[buf^1][i] = src[i];
    }
    for (int lc=0;lc<SCH;lc++){
      int l = c*SCH + lc;
      size_t t = tbase + l;
      float xraw = xb_n, zv = z_n;
      if (l+1 < LSEQ){
        xb_n = b2f(xb[(t+1)*DI + d]);
        z_n  = b2f(z [(t+1)*DI + d]);
      }
      const float* sp = &sxp[buf][lc*(2*DS+1)];
      float conv = cbd + w0*f0 + w1*f1 + w2*f2 + w3*xraw;
      float xt = silu(conv);
      float dl = sp[0]*dtw + dtb;
      float delta = (dl > 20.f) ? dl : log1pf(__expf(dl));
      float dx = delta*xt;
      float y=0.f;
      #pragma unroll
      for (int n=0;n<DS;n++){
        float dA = __expf(delta*A[n]);
        h[n] = dA*h[n] + dx*sp[1+n];
        y += h[n]*sp[1+DS+n];
      }
      y += Dd*xt;
      xb[t*DI + d] = f2b(y*silu(zv));
      f0=f1; f1=f2; f2=xraw;
    }
    __syncthreads();
  }
}

extern "C" void kernel_launch(void* const* d_in, const int* in_sizes, int n_in,
                              void* d_out, int out_size, void* d_ws, size_t ws_size,
                              hipStream_t stream) {
  const float* x        = (const float*)d_in[0];
  const float* ln_g     = (const float*)d_in[1];
  const float* ln_b     = (const float*)d_in[2];
  const float* in_w     = (const float*)d_in[3];
  const float* conv_w   = (const float*)d_in[4];
  const float* conv_b   = (const float*)d_in[5];
  const float* xproj_w  = (const float*)d_in[6];
  const float* dt_w     = (const float*)d_in[7];
  const float* dt_b     = (const float*)d_in[8];
  const float* A_log    = (const float*)d_in[9];
  const float* Dp       = (const float*)d_in[10];
  const float* out_w    = (const float*)d_in[11];
  float* out = (float*)d_out;

  // workspace layout (~103 MB, proven mapped):
  float* stats = (float*)d_ws;                         // NT*2 fp32
  float* xp    = stats + (size_t)NT*2;                 // NT*33 fp32
  bf16*  xbuf  = (bf16*)(xp + (size_t)NT*(2*DS+1));    // NT*DI bf16 (xb -> ys)
  bf16*  zbuf  = xbuf + (size_t)NT*DI;                 // NT*DI bf16

  ln_stats<<<NT/4, 256, 0, stream>>>(x, stats);

  gemm_in_mfma<<<dim3(2*DI/128, NT/128), 256, 0, stream>>>(
      x, stats, ln_g, ln_b, in_w, xbuf, zbuf);

  xproj_conv<<<NT, 64, 0, stream>>>(xbuf, conv_w, conv_b, xproj_w, xp);

  scan_fused<<<dim3(DI/64, NB), 64, 0, stream>>>(
      xp, zbuf, conv_w, conv_b, dt_w, dt_b, A_log, Dp, xbuf);

  gemm_out_mfma<<<dim3(DM/128, NT/128), 256, 0, stream>>>(xbuf, out_w, x, out);
}

// Round 6
// 2527.679 us; speedup vs baseline: 4.0713x; 1.1113x over previous
//
#include <hip/hip_runtime.h>
#include <hip/hip_bf16.h>

#define NB 8
#define LSEQ 2048
#define DM 768
#define DI 1536
#define DS 16
#define NT (NB*LSEQ)   // 16384 tokens

typedef __hip_bfloat16 bf16;
typedef __bf16 bf16x8 __attribute__((ext_vector_type(8)));
typedef float  f32x4  __attribute__((ext_vector_type(4)));

__device__ __forceinline__ float b2f(bf16 v){ return __bfloat162float(v); }
__device__ __forceinline__ bf16  f2b(float v){ return __float2bfloat16(v); }
__device__ __forceinline__ float silu(float v){ return v/(1.f+__expf(-v)); }

// ---------------- LN stats: one wave per token ----------------
__global__ void ln_stats(const float* __restrict__ x, float* __restrict__ stats){
  int wv = threadIdx.x>>6, ln = threadIdx.x&63;
  int t = blockIdx.x*4 + wv;
  const float* xr = x + (size_t)t*DM;
  float s=0.f, s2=0.f;
  for (int i=ln;i<DM;i+=64){ float v=xr[i]; s+=v; s2+=v*v; }
  #pragma unroll
  for (int o=32;o>0;o>>=1){ s+=__shfl_down(s,o); s2+=__shfl_down(s2,o); }
  if (ln==0){
    float mean = s/(float)DM;
    stats[2*t]   = mean;
    stats[2*t+1] = rsqrtf(s2/(float)DM - mean*mean + 1e-5f);
  }
}

// ---------------- in_proj MFMA GEMM with LN fused ----------------
// xb/z bf16 [NT,DI] = LN(x)[NT,768] @ W[3072,768]^T, split at col 1536.
// grid (3072/128=24, NT/128=128), block 256 (4 waves, 2x2 of 64x64).
__global__ __launch_bounds__(256) void gemm_in_mfma(
    const float* __restrict__ x, const float* __restrict__ stats,
    const float* __restrict__ g, const float* __restrict__ bb,
    const float* __restrict__ W,
    bf16* __restrict__ xb, bf16* __restrict__ z){
  __shared__ __align__(16) bf16 sA[128][40];   // pad +8 bf16: stride 80B = 5x16B
  __shared__ __align__(16) bf16 sW[128][40];
  int tid = threadIdx.x;
  int m0 = blockIdx.y*128, n0 = blockIdx.x*128;
  int sr = tid>>1, sc = (tid&1)*16;
  int arow = m0 + sr;
  float mean = stats[2*arow], rstd = stats[2*arow+1];
  int wave = tid>>6, lane = tid&63;
  int wm = (wave>>1)*64, wn = (wave&1)*64;
  int lr = lane&15, kq = lane>>4;
  f32x4 acc[4][4];
  #pragma unroll
  for (int i=0;i<4;i++)
    #pragma unroll
    for (int j=0;j<4;j++) acc[i][j] = (f32x4){0.f,0.f,0.f,0.f};

  for (int k0=0;k0<DM;k0+=32){
    const float4* xs   = (const float4*)(x  + (size_t)arow*DM + k0 + sc);
    const float4* gs   = (const float4*)(g  + k0 + sc);
    const float4* bs   = (const float4*)(bb + k0 + sc);
    const float4* wsrc = (const float4*)(W  + (size_t)(n0+sr)*DM + k0 + sc);
    bf16 ta[16] __attribute__((aligned(16)));
    bf16 tw[16] __attribute__((aligned(16)));
    #pragma unroll
    for (int u=0;u<4;u++){
      float4 xv=xs[u], gv=gs[u], bv=bs[u], wv=wsrc[u];
      ta[4*u+0]=f2b((xv.x-mean)*rstd*gv.x+bv.x);
      ta[4*u+1]=f2b((xv.y-mean)*rstd*gv.y+bv.y);
      ta[4*u+2]=f2b((xv.z-mean)*rstd*gv.z+bv.z);
      ta[4*u+3]=f2b((xv.w-mean)*rstd*gv.w+bv.w);
      tw[4*u+0]=f2b(wv.x); tw[4*u+1]=f2b(wv.y);
      tw[4*u+2]=f2b(wv.z); tw[4*u+3]=f2b(wv.w);
    }
    *(uint4*)&sA[sr][sc]   = ((uint4*)ta)[0];
    *(uint4*)&sA[sr][sc+8] = ((uint4*)ta)[1];
    *(uint4*)&sW[sr][sc]   = ((uint4*)tw)[0];
    *(uint4*)&sW[sr][sc+8] = ((uint4*)tw)[1];
    __syncthreads();
    bf16x8 af[4], bfr[4];
    #pragma unroll
    for (int i=0;i<4;i++) af[i]  = *(const bf16x8*)&sA[wm+i*16+lr][kq*8];
    #pragma unroll
    for (int j=0;j<4;j++) bfr[j] = *(const bf16x8*)&sW[wn+j*16+lr][kq*8];
    #pragma unroll
    for (int i=0;i<4;i++)
      #pragma unroll
      for (int j=0;j<4;j++)
        acc[i][j] = __builtin_amdgcn_mfma_f32_16x16x32_bf16(af[i], bfr[j], acc[i][j], 0,0,0);
    __syncthreads();
  }
  #pragma unroll
  for (int i=0;i<4;i++){
    #pragma unroll
    for (int j=0;j<4;j++){
      int colg = n0 + wn + j*16 + lr;
      #pragma unroll
      for (int r=0;r<4;r++){
        int rowg = m0 + wm + i*16 + kq*4 + r;
        float v = acc[i][j][r];
        if (colg < DI) xb[(size_t)rowg*DI + colg]      = f2b(v);
        else           z [(size_t)rowg*DI + colg - DI] = f2b(v);
      }
    }
  }
}

// ---------------- out_proj MFMA GEMM + residual, fp32 out ----------------
// out[NT,768] = ys[NT,1536](bf16) @ Wo[768,1536]^T + xres
// grid (768/128=6, NT/128=128), block 256.
__global__ __launch_bounds__(256) void gemm_out_mfma(
    const bf16* __restrict__ ys, const float* __restrict__ W,
    const float* __restrict__ xres, float* __restrict__ out){
  __shared__ __align__(16) bf16 sA[128][40];
  __shared__ __align__(16) bf16 sW[128][40];
  int tid = threadIdx.x;
  int m0 = blockIdx.y*128, n0 = blockIdx.x*128;
  int sr = tid>>1, sc = (tid&1)*16;
  int wave = tid>>6, lane = tid&63;
  int wm = (wave>>1)*64, wn = (wave&1)*64;
  int lr = lane&15, kq = lane>>4;
  f32x4 acc[4][4];
  #pragma unroll
  for (int i=0;i<4;i++)
    #pragma unroll
    for (int j=0;j<4;j++) acc[i][j] = (f32x4){0.f,0.f,0.f,0.f};

  for (int k0=0;k0<DI;k0+=32){
    const uint4* asrc = (const uint4*)(ys + (size_t)(m0+sr)*DI + k0 + sc);
    uint4 a0 = asrc[0], a1 = asrc[1];
    const float4* wsrc = (const float4*)(W + (size_t)(n0+sr)*DI + k0 + sc);
    bf16 tw[16] __attribute__((aligned(16)));
    #pragma unroll
    for (int u=0;u<4;u++){
      float4 wv=wsrc[u];
      tw[4*u+0]=f2b(wv.x); tw[4*u+1]=f2b(wv.y);
      tw[4*u+2]=f2b(wv.z); tw[4*u+3]=f2b(wv.w);
    }
    *(uint4*)&sA[sr][sc]   = a0;
    *(uint4*)&sA[sr][sc+8] = a1;
    *(uint4*)&sW[sr][sc]   = ((uint4*)tw)[0];
    *(uint4*)&sW[sr][sc+8] = ((uint4*)tw)[1];
    __syncthreads();
    bf16x8 af[4], bfr[4];
    #pragma unroll
    for (int i=0;i<4;i++) af[i]  = *(const bf16x8*)&sA[wm+i*16+lr][kq*8];
    #pragma unroll
    for (int j=0;j<4;j++) bfr[j] = *(const bf16x8*)&sW[wn+j*16+lr][kq*8];
    #pragma unroll
    for (int i=0;i<4;i++)
      #pragma unroll
      for (int j=0;j<4;j++)
        acc[i][j] = __builtin_amdgcn_mfma_f32_16x16x32_bf16(af[i], bfr[j], acc[i][j], 0,0,0);
    __syncthreads();
  }
  #pragma unroll
  for (int i=0;i<4;i++){
    #pragma unroll
    for (int j=0;j<4;j++){
      int colg = n0 + wn + j*16 + lr;
      #pragma unroll
      for (int r=0;r<4;r++){
        int rowg = m0 + wm + i*16 + kq*4 + r;
        out[(size_t)rowg*DM + colg] = acc[i][j][r] + xres[(size_t)rowg*DM + colg];
      }
    }
  }
}

// ---------------- x_proj with conv+SiLU fused (float4) ----------------
__global__ __launch_bounds__(64) void xproj_conv(const bf16* __restrict__ xbuf,
                           const float* __restrict__ cw,
                           const float* __restrict__ cb, const float* __restrict__ Wx,
                           float* __restrict__ xp){
  __shared__ __align__(16) float row[DI];
  int t = blockIdx.x;
  int l = t % LSEQ;
  const bf16* x0 = xbuf + (size_t)t*DI;
  for (int i=threadIdx.x;i<DI;i+=64){
    float acc = cb[i];
    acc += b2f(x0[i]) * cw[i*4+3];
    if (l>=1) acc += b2f(x0[i-(size_t)DI  ]) * cw[i*4+2];
    if (l>=2) acc += b2f(x0[i-(size_t)2*DI]) * cw[i*4+1];
    if (l>=3) acc += b2f(x0[i-(size_t)3*DI]) * cw[i*4+0];
    row[i] = silu(acc);
  }
  __syncthreads();
  int j = threadIdx.x;
  if (j < 2*DS+1){
    const float4* wr = (const float4*)(Wx + (size_t)j*DI);
    const float4* rw = (const float4*)row;
    float acc=0.f;
    #pragma unroll 4
    for (int k=0;k<DI/4;k++){
      float4 a=rw[k], w=wr[k];
      acc += a.x*w.x + a.y*w.y + a.z*w.z + a.w*w.w;
    }
    xp[(size_t)t*(2*DS+1) + j] = acc;
  }
}

// ---------------- selective scan v3: 8-token-deep load pipeline ----------------
// grid (DI/64, NB), block 64 (one wave). Latency-bound fix: 16 outstanding
// scalar loads (8 tokens of xb + z) issued ahead of each 8-token compute group.
#define SCH 64
#define PF 8
__global__ __launch_bounds__(64) void scan_fused(
    const float* __restrict__ xp, const bf16* __restrict__ z,
    const float* __restrict__ cw, const float* __restrict__ cb,
    const float* __restrict__ dt_w, const float* __restrict__ dt_b,
    const float* __restrict__ A_log, const float* __restrict__ Dp,
    bf16* __restrict__ xb /* in: xb, out: gated ys */){
  int tid = threadIdx.x;
  int d = blockIdx.x*64 + tid;
  int b = blockIdx.y;
  float A[DS];
  #pragma unroll
  for (int n=0;n<DS;n++) A[n] = -expf(A_log[(size_t)d*DS+n]);
  float dtw = dt_w[d], dtb = dt_b[d], Dd = Dp[d];
  float w0=cw[d*4+0], w1=cw[d*4+1], w2=cw[d*4+2], w3=cw[d*4+3];
  float cbd=cb[d];
  float f0=0.f, f1=0.f, f2=0.f;
  float h[DS];
  #pragma unroll
  for (int n=0;n<DS;n++) h[n]=0.f;
  __shared__ float sxp[2][SCH*(2*DS+1)];
  const float* xpb = xp + (size_t)b*LSEQ*(2*DS+1);
  for (int i=tid;i<SCH*(2*DS+1);i+=64) sxp[0][i] = xpb[i];
  size_t base = (size_t)b*LSEQ*DI + d;    // elem index of (b, t=0, d)
  // prime the pipeline: tokens 0..PF-1
  float xbv[PF], zvv[PF];
  #pragma unroll
  for (int k=0;k<PF;k++){
    xbv[k] = b2f(xb[base + (size_t)k*DI]);
    zvv[k] = b2f(z [base + (size_t)k*DI]);
  }
  __syncthreads();
  const int NCH = LSEQ/SCH;
  for (int c=0;c<NCH;c++){
    int buf = c&1;
    if (c+1 < NCH){
      const float* src = xpb + (size_t)(c+1)*SCH*(2*DS+1);
      for (int i=tid;i<SCH*(2*DS+1);i+=64) sxp[buf^1][i] = src[i];
    }
    for (int gdx=0; gdx<SCH/PF; gdx++){
      // issue next PF tokens' loads (16 outstanding) before computing this group
      float xbn[PF], zn[PF];
      int tnext = c*SCH + (gdx+1)*PF;
      if (tnext < LSEQ){
        #pragma unroll
        for (int k=0;k<PF;k++){
          xbn[k] = b2f(xb[base + (size_t)(tnext+k)*DI]);
          zn[k]  = b2f(z [base + (size_t)(tnext+k)*DI]);
        }
      } else {
        #pragma unroll
        for (int k=0;k<PF;k++){ xbn[k]=0.f; zn[k]=0.f; }
      }
      #pragma unroll
      for (int k=0;k<PF;k++){
        int lc = gdx*PF + k;
        size_t t = (size_t)b*LSEQ + c*SCH + lc;
        const float* sp = &sxp[buf][lc*(2*DS+1)];
        float xraw = xbv[k];
        float conv = cbd + w0*f0 + w1*f1 + w2*f2 + w3*xraw;
        float xt = silu(conv);
        float dl = sp[0]*dtw + dtb;
        float delta = (dl > 20.f) ? dl : log1pf(__expf(dl));
        float dx = delta*xt;
        float y=0.f;
        #pragma unroll
        for (int n=0;n<DS;n++){
          float dA = __expf(delta*A[n]);
          h[n] = dA*h[n] + dx*sp[1+n];
          y += h[n]*sp[1+DS+n];
        }
        y += Dd*xt;
        xb[t*DI + d] = f2b(y*silu(zvv[k]));
        f0=f1; f1=f2; f2=xraw;
      }
      #pragma unroll
      for (int k=0;k<PF;k++){ xbv[k]=xbn[k]; zvv[k]=zn[k]; }
    }
    __syncthreads();
  }
}

extern "C" void kernel_launch(void* const* d_in, const int* in_sizes, int n_in,
                              void* d_out, int out_size, void* d_ws, size_t ws_size,
                              hipStream_t stream) {
  const float* x        = (const float*)d_in[0];
  const float* ln_g     = (const float*)d_in[1];
  const float* ln_b     = (const float*)d_in[2];
  const float* in_w     = (const float*)d_in[3];
  const float* conv_w   = (const float*)d_in[4];
  const float* conv_b   = (const float*)d_in[5];
  const float* xproj_w  = (const float*)d_in[6];
  const float* dt_w     = (const float*)d_in[7];
  const float* dt_b     = (const float*)d_in[8];
  const float* A_log    = (const float*)d_in[9];
  const float* Dp       = (const float*)d_in[10];
  const float* out_w    = (const float*)d_in[11];
  float* out = (float*)d_out;

  // workspace layout (~103 MB, proven mapped):
  float* stats = (float*)d_ws;                         // NT*2 fp32
  float* xp    = stats + (size_t)NT*2;                 // NT*33 fp32
  bf16*  xbuf  = (bf16*)(xp + (size_t)NT*(2*DS+1));    // NT*DI bf16 (xb -> ys)
  bf16*  zbuf  = xbuf + (size_t)NT*DI;                 // NT*DI bf16

  ln_stats<<<NT/4, 256, 0, stream>>>(x, stats);

  gemm_in_mfma<<<dim3(2*DI/128, NT/128), 256, 0, stream>>>(
      x, stats, ln_g, ln_b, in_w, xbuf, zbuf);

  xproj_conv<<<NT, 64, 0, stream>>>(xbuf, conv_w, conv_b, xproj_w, xp);

  scan_fused<<<dim3(DI/64, NB), 64, 0, stream>>>(
      xp, zbuf, conv_w, conv_b, dt_w, dt_b, A_log, Dp, xbuf);

  gemm_out_mfma<<<dim3(DM/128, NT/128), 256, 0, stream>>>(xbuf, out_w, x, out);
}

// Round 7
// 1481.552 us; speedup vs baseline: 6.9460x; 1.7061x over previous
//
#include <hip/hip_runtime.h>
#include <hip/hip_bf16.h>

#define NB 8
#define LSEQ 2048
#define DM 768
#define DI 1536
#define DS 16
#define NT (NB*LSEQ)   // 16384 tokens
#define NC 32          // scan chunks per sequence
#define CHL (LSEQ/NC)  // 64 tokens per chunk

typedef __hip_bfloat16 bf16;
typedef __bf16 bf16x8 __attribute__((ext_vector_type(8)));
typedef float  f32x4  __attribute__((ext_vector_type(4)));

__device__ __forceinline__ float b2f(bf16 v){ return __bfloat162float(v); }
__device__ __forceinline__ bf16  f2b(float v){ return __float2bfloat16(v); }
__device__ __forceinline__ float silu(float v){ return v/(1.f+__expf(-v)); }

// ---------------- LN stats: one wave per token ----------------
__global__ void ln_stats(const float* __restrict__ x, float* __restrict__ stats){
  int wv = threadIdx.x>>6, ln = threadIdx.x&63;
  int t = blockIdx.x*4 + wv;
  const float* xr = x + (size_t)t*DM;
  float s=0.f, s2=0.f;
  for (int i=ln;i<DM;i+=64){ float v=xr[i]; s+=v; s2+=v*v; }
  #pragma unroll
  for (int o=32;o>0;o>>=1){ s+=__shfl_down(s,o); s2+=__shfl_down(s2,o); }
  if (ln==0){
    float mean = s/(float)DM;
    stats[2*t]   = mean;
    stats[2*t+1] = rsqrtf(s2/(float)DM - mean*mean + 1e-5f);
  }
}

// ---------------- in_proj MFMA GEMM with LN fused ----------------
__global__ __launch_bounds__(256) void gemm_in_mfma(
    const float* __restrict__ x, const float* __restrict__ stats,
    const float* __restrict__ g, const float* __restrict__ bb,
    const float* __restrict__ W,
    bf16* __restrict__ xb, bf16* __restrict__ z){
  __shared__ __align__(16) bf16 sA[128][40];
  __shared__ __align__(16) bf16 sW[128][40];
  int tid = threadIdx.x;
  int m0 = blockIdx.y*128, n0 = blockIdx.x*128;
  int sr = tid>>1, sc = (tid&1)*16;
  int arow = m0 + sr;
  float mean = stats[2*arow], rstd = stats[2*arow+1];
  int wave = tid>>6, lane = tid&63;
  int wm = (wave>>1)*64, wn = (wave&1)*64;
  int lr = lane&15, kq = lane>>4;
  f32x4 acc[4][4];
  #pragma unroll
  for (int i=0;i<4;i++)
    #pragma unroll
    for (int j=0;j<4;j++) acc[i][j] = (f32x4){0.f,0.f,0.f,0.f};

  for (int k0=0;k0<DM;k0+=32){
    const float4* xs   = (const float4*)(x  + (size_t)arow*DM + k0 + sc);
    const float4* gs   = (const float4*)(g  + k0 + sc);
    const float4* bs   = (const float4*)(bb + k0 + sc);
    const float4* wsrc = (const float4*)(W  + (size_t)(n0+sr)*DM + k0 + sc);
    bf16 ta[16] __attribute__((aligned(16)));
    bf16 tw[16] __attribute__((aligned(16)));
    #pragma unroll
    for (int u=0;u<4;u++){
      float4 xv=xs[u], gv=gs[u], bv=bs[u], wv=wsrc[u];
      ta[4*u+0]=f2b((xv.x-mean)*rstd*gv.x+bv.x);
      ta[4*u+1]=f2b((xv.y-mean)*rstd*gv.y+bv.y);
      ta[4*u+2]=f2b((xv.z-mean)*rstd*gv.z+bv.z);
      ta[4*u+3]=f2b((xv.w-mean)*rstd*gv.w+bv.w);
      tw[4*u+0]=f2b(wv.x); tw[4*u+1]=f2b(wv.y);
      tw[4*u+2]=f2b(wv.z); tw[4*u+3]=f2b(wv.w);
    }
    *(uint4*)&sA[sr][sc]   = ((uint4*)ta)[0];
    *(uint4*)&sA[sr][sc+8] = ((uint4*)ta)[1];
    *(uint4*)&sW[sr][sc]   = ((uint4*)tw)[0];
    *(uint4*)&sW[sr][sc+8] = ((uint4*)tw)[1];
    __syncthreads();
    bf16x8 af[4], bfr[4];
    #pragma unroll
    for (int i=0;i<4;i++) af[i]  = *(const bf16x8*)&sA[wm+i*16+lr][kq*8];
    #pragma unroll
    for (int j=0;j<4;j++) bfr[j] = *(const bf16x8*)&sW[wn+j*16+lr][kq*8];
    #pragma unroll
    for (int i=0;i<4;i++)
      #pragma unroll
      for (int j=0;j<4;j++)
        acc[i][j] = __builtin_amdgcn_mfma_f32_16x16x32_bf16(af[i], bfr[j], acc[i][j], 0,0,0);
    __syncthreads();
  }
  #pragma unroll
  for (int i=0;i<4;i++){
    #pragma unroll
    for (int j=0;j<4;j++){
      int colg = n0 + wn + j*16 + lr;
      #pragma unroll
      for (int r=0;r<4;r++){
        int rowg = m0 + wm + i*16 + kq*4 + r;
        float v = acc[i][j][r];
        if (colg < DI) xb[(size_t)rowg*DI + colg]      = f2b(v);
        else           z [(size_t)rowg*DI + colg - DI] = f2b(v);
      }
    }
  }
}

// ---------------- out_proj MFMA GEMM + residual, fp32 out ----------------
__global__ __launch_bounds__(256) void gemm_out_mfma(
    const bf16* __restrict__ ys, const float* __restrict__ W,
    const float* __restrict__ xres, float* __restrict__ out){
  __shared__ __align__(16) bf16 sA[128][40];
  __shared__ __align__(16) bf16 sW[128][40];
  int tid = threadIdx.x;
  int m0 = blockIdx.y*128, n0 = blockIdx.x*128;
  int sr = tid>>1, sc = (tid&1)*16;
  int wave = tid>>6, lane = tid&63;
  int wm = (wave>>1)*64, wn = (wave&1)*64;
  int lr = lane&15, kq = lane>>4;
  f32x4 acc[4][4];
  #pragma unroll
  for (int i=0;i<4;i++)
    #pragma unroll
    for (int j=0;j<4;j++) acc[i][j] = (f32x4){0.f,0.f,0.f,0.f};

  for (int k0=0;k0<DI;k0+=32){
    const uint4* asrc = (const uint4*)(ys + (size_t)(m0+sr)*DI + k0 + sc);
    uint4 a0 = asrc[0], a1 = asrc[1];
    const float4* wsrc = (const float4*)(W + (size_t)(n0+sr)*DI + k0 + sc);
    bf16 tw[16] __attribute__((aligned(16)));
    #pragma unroll
    for (int u=0;u<4;u++){
      float4 wv=wsrc[u];
      tw[4*u+0]=f2b(wv.x); tw[4*u+1]=f2b(wv.y);
      tw[4*u+2]=f2b(wv.z); tw[4*u+3]=f2b(wv.w);
    }
    *(uint4*)&sA[sr][sc]   = a0;
    *(uint4*)&sA[sr][sc+8] = a1;
    *(uint4*)&sW[sr][sc]   = ((uint4*)tw)[0];
    *(uint4*)&sW[sr][sc+8] = ((uint4*)tw)[1];
    __syncthreads();
    bf16x8 af[4], bfr[4];
    #pragma unroll
    for (int i=0;i<4;i++) af[i]  = *(const bf16x8*)&sA[wm+i*16+lr][kq*8];
    #pragma unroll
    for (int j=0;j<4;j++) bfr[j] = *(const bf16x8*)&sW[wn+j*16+lr][kq*8];
    #pragma unroll
    for (int i=0;i<4;i++)
      #pragma unroll
      for (int j=0;j<4;j++)
        acc[i][j] = __builtin_amdgcn_mfma_f32_16x16x32_bf16(af[i], bfr[j], acc[i][j], 0,0,0);
    __syncthreads();
  }
  #pragma unroll
  for (int i=0;i<4;i++){
    #pragma unroll
    for (int j=0;j<4;j++){
      int colg = n0 + wn + j*16 + lr;
      #pragma unroll
      for (int r=0;r<4;r++){
        int rowg = m0 + wm + i*16 + kq*4 + r;
        out[(size_t)rowg*DM + colg] = acc[i][j][r] + xres[(size_t)rowg*DM + colg];
      }
    }
  }
}

// ---------------- x_proj with conv+SiLU fused (float4) ----------------
__global__ __launch_bounds__(64) void xproj_conv(const bf16* __restrict__ xbuf,
                           const float* __restrict__ cw,
                           const float* __restrict__ cb, const float* __restrict__ Wx,
                           float* __restrict__ xp){
  __shared__ __align__(16) float row[DI];
  int t = blockIdx.x;
  int l = t % LSEQ;
  const bf16* x0 = xbuf + (size_t)t*DI;
  for (int i=threadIdx.x;i<DI;i+=64){
    float acc = cb[i];
    acc += b2f(x0[i]) * cw[i*4+3];
    if (l>=1) acc += b2f(x0[i-(size_t)DI  ]) * cw[i*4+2];
    if (l>=2) acc += b2f(x0[i-(size_t)2*DI]) * cw[i*4+1];
    if (l>=3) acc += b2f(x0[i-(size_t)3*DI]) * cw[i*4+0];
    row[i] = silu(acc);
  }
  __syncthreads();
  int j = threadIdx.x;
  if (j < 2*DS+1){
    const float4* wr = (const float4*)(Wx + (size_t)j*DI);
    const float4* rw = (const float4*)row;
    float acc=0.f;
    #pragma unroll 4
    for (int k=0;k<DI/4;k++){
      float4 a=rw[k], w=wr[k];
      acc += a.x*w.x + a.y*w.y + a.z*w.z + a.w*w.w;
    }
    xp[(size_t)t*(2*DS+1) + j] = acc;
  }
}

// ---------------- chunked selective scan ----------------
// Recurrence h_t = a_t h_{t-1} + u_t, a_t = exp(delta_t*A), u_t = delta_t*xt_t*B_t.
// Over a chunk: h_end = exp(A*Sum(delta)) * h_start + h_local.
// part1: per-chunk local scan from h=0 -> (S, h_local).  part2: sequential
// combine over 32 chunks -> overwrite state with true h_start per chunk.
// part3: replay chunk from h_start, compute y, gate, write into z.

// grid (DI/64, NB, NC), block 64
__global__ __launch_bounds__(64) void scan_part1(
    const float* __restrict__ xp, const bf16* __restrict__ xb,
    const float* __restrict__ cw, const float* __restrict__ cb,
    const float* __restrict__ dt_w, const float* __restrict__ dt_b,
    const float* __restrict__ A_log,
    float* __restrict__ Ssum, float* __restrict__ Hst){
  int tid = threadIdx.x;
  int d = blockIdx.x*64 + tid;
  int b = blockIdx.y, c = blockIdx.z;
  int l0 = c*CHL;
  size_t tbase = (size_t)b*LSEQ;
  __shared__ float sxp[CHL*33];
  __shared__ bf16  sxb[CHL][64];
  const float* xps = xp + (tbase + l0)*33;
  for (int i=tid;i<CHL*33;i+=64) sxp[i] = xps[i];
  const bf16* xbs = xb + (tbase + l0)*DI + (size_t)blockIdx.x*64;
  for (int i=tid;i<CHL*16;i+=64){
    int t = i>>4, q = i&15;
    ((uint2*)&sxb[t][0])[q] = *(const uint2*)(xbs + (size_t)t*DI + q*4);
  }
  float A[DS];
  #pragma unroll
  for (int n=0;n<DS;n++) A[n] = -expf(A_log[(size_t)d*DS+n]);
  float dtw = dt_w[d], dtb = dt_b[d];
  float w0=cw[d*4+0], w1=cw[d*4+1], w2=cw[d*4+2], w3=cw[d*4+3];
  float cbd=cb[d];
  float f2 = (l0>=1)? b2f(xb[(tbase+l0-1)*DI+d]) : 0.f;
  float f1 = (l0>=2)? b2f(xb[(tbase+l0-2)*DI+d]) : 0.f;
  float f0 = (l0>=3)? b2f(xb[(tbase+l0-3)*DI+d]) : 0.f;
  float h[DS];
  #pragma unroll
  for (int n=0;n<DS;n++) h[n]=0.f;
  float S=0.f;
  __syncthreads();
  for (int lc=0;lc<CHL;lc++){
    float xraw = b2f(sxb[lc][tid]);
    float conv = cbd + w0*f0 + w1*f1 + w2*f2 + w3*xraw;
    float xt = silu(conv);
    const float* sp = &sxp[lc*33];
    float dl = sp[0]*dtw + dtb;
    float delta = (dl > 20.f) ? dl : log1pf(__expf(dl));
    S += delta;
    float dx = delta*xt;
    #pragma unroll
    for (int n=0;n<DS;n++)
      h[n] = __expf(delta*A[n])*h[n] + dx*sp[1+n];
    f0=f1; f1=f2; f2=xraw;
  }
  size_t sidx = ((size_t)(b*NC+c))*DI + d;
  Ssum[sidx] = S;
  #pragma unroll
  for (int n=0;n<DS;n++)
    Hst[((size_t)(b*NC+c)*DS+n)*DI + d] = h[n];
}

// grid (NB*DI/256), block 256: thread = (b,d); sequential over 32 chunks.
__global__ __launch_bounds__(256) void scan_part2(
    const float* __restrict__ A_log,
    const float* __restrict__ Ssum, float* __restrict__ Hst){
  int gid = blockIdx.x*256 + threadIdx.x;
  int b = gid / DI, d = gid % DI;
  float A[DS];
  #pragma unroll
  for (int n=0;n<DS;n++) A[n] = -expf(A_log[(size_t)d*DS+n]);
  float h[DS];
  #pragma unroll
  for (int n=0;n<DS;n++) h[n]=0.f;
  for (int c=0;c<NC;c++){
    float S = Ssum[((size_t)(b*NC+c))*DI + d];
    #pragma unroll
    for (int n=0;n<DS;n++){
      size_t hidx = ((size_t)(b*NC+c)*DS+n)*DI + d;
      float hl = Hst[hidx];
      Hst[hidx] = h[n];                       // true h_start for chunk c
      h[n] = __expf(S*A[n])*h[n] + hl;        // state after chunk c
    }
  }
}

// grid (DI/64, NB, NC), block 64. Replay from h_start; write gated y into z.
__global__ __launch_bounds__(64) void scan_part3(
    const float* __restrict__ xp, const bf16* __restrict__ xb,
    bf16* __restrict__ z,
    const float* __restrict__ cw, const float* __restrict__ cb,
    const float* __restrict__ dt_w, const float* __restrict__ dt_b,
    const float* __restrict__ A_log, const float* __restrict__ Dp,
    const float* __restrict__ Hst){
  int tid = threadIdx.x;
  int d = blockIdx.x*64 + tid;
  int b = blockIdx.y, c = blockIdx.z;
  int l0 = c*CHL;
  size_t tbase = (size_t)b*LSEQ;
  __shared__ float sxp[CHL*33];
  __shared__ bf16  sxb[CHL][64];
  const float* xps = xp + (tbase + l0)*33;
  for (int i=tid;i<CHL*33;i+=64) sxp[i] = xps[i];
  const bf16* xbs = xb + (tbase + l0)*DI + (size_t)blockIdx.x*64;
  for (int i=tid;i<CHL*16;i+=64){
    int t = i>>4, q = i&15;
    ((uint2*)&sxb[t][0])[q] = *(const uint2*)(xbs + (size_t)t*DI + q*4);
  }
  float A[DS];
  #pragma unroll
  for (int n=0;n<DS;n++) A[n] = -expf(A_log[(size_t)d*DS+n]);
  float dtw = dt_w[d], dtb = dt_b[d], Dd = Dp[d];
  float w0=cw[d*4+0], w1=cw[d*4+1], w2=cw[d*4+2], w3=cw[d*4+3];
  float cbd=cb[d];
  float f2 = (l0>=1)? b2f(xb[(tbase+l0-1)*DI+d]) : 0.f;
  float f1 = (l0>=2)? b2f(xb[(tbase+l0-2)*DI+d]) : 0.f;
  float f0 = (l0>=3)? b2f(xb[(tbase+l0-3)*DI+d]) : 0.f;
  float h[DS];
  #pragma unroll
  for (int n=0;n<DS;n++) h[n] = Hst[((size_t)(b*NC+c)*DS+n)*DI + d];
  __syncthreads();
  for (int lc=0;lc<CHL;lc++){
    size_t t = tbase + l0 + lc;
    float zv = b2f(z[t*DI + d]);
    float xraw = b2f(sxb[lc][tid]);
    float conv = cbd + w0*f0 + w1*f1 + w2*f2 + w3*xraw;
    float xt = silu(conv);
    const float* sp = &sxp[lc*33];
    float dl = sp[0]*dtw + dtb;
    float delta = (dl > 20.f) ? dl : log1pf(__expf(dl));
    float dx = delta*xt;
    float y=0.f;
    #pragma unroll
    for (int n=0;n<DS;n++){
      h[n] = __expf(delta*A[n])*h[n] + dx*sp[1+n];
      y += h[n]*sp[1+DS+n];
    }
    y += Dd*xt;
    z[t*DI + d] = f2b(y*silu(zv));
    f0=f1; f1=f2; f2=xraw;
  }
}

extern "C" void kernel_launch(void* const* d_in, const int* in_sizes, int n_in,
                              void* d_out, int out_size, void* d_ws, size_t ws_size,
                              hipStream_t stream) {
  const float* x        = (const float*)d_in[0];
  const float* ln_g     = (const float*)d_in[1];
  const float* ln_b     = (const float*)d_in[2];
  const float* in_w     = (const float*)d_in[3];
  const float* conv_w   = (const float*)d_in[4];
  const float* conv_b   = (const float*)d_in[5];
  const float* xproj_w  = (const float*)d_in[6];
  const float* dt_w     = (const float*)d_in[7];
  const float* dt_b     = (const float*)d_in[8];
  const float* A_log    = (const float*)d_in[9];
  const float* Dp       = (const float*)d_in[10];
  const float* out_w    = (const float*)d_in[11];
  float* out = (float*)d_out;

  // workspace layout (~103 MB, proven mapped):
  float* stats = (float*)d_ws;                         // NT*2 fp32
  float* xp    = stats + (size_t)NT*2;                 // NT*33 fp32
  bf16*  xbuf  = (bf16*)(xp + (size_t)NT*(2*DS+1));    // NT*DI bf16 (stays raw xb)
  bf16*  zbuf  = xbuf + (size_t)NT*DI;                 // NT*DI bf16 (z -> gated ys)

  // scan state scratch inside d_out (free until gemm_out): 26.7 MB < 50.3 MB
  float* Ssum = out;                                   // NB*NC*DI fp32
  float* Hst  = out + (size_t)NB*NC*DI;                // NB*NC*DS*DI fp32

  ln_stats<<<NT/4, 256, 0, stream>>>(x, stats);

  gemm_in_mfma<<<dim3(2*DI/128, NT/128), 256, 0, stream>>>(
      x, stats, ln_g, ln_b, in_w, xbuf, zbuf);

  xproj_conv<<<NT, 64, 0, stream>>>(xbuf, conv_w, conv_b, xproj_w, xp);

  scan_part1<<<dim3(DI/64, NB, NC), 64, 0, stream>>>(
      xp, xbuf, conv_w, conv_b, dt_w, dt_b, A_log, Ssum, Hst);

  scan_part2<<<NB*DI/256, 256, 0, stream>>>(A_log, Ssum, Hst);

  scan_part3<<<dim3(DI/64, NB, NC), 64, 0, stream>>>(
      xp, xbuf, zbuf, conv_w, conv_b, dt_w, dt_b, A_log, Dp, Hst);

  gemm_out_mfma<<<dim3(DM/128, NT/128), 256, 0, stream>>>(zbuf, out_w, x, out);
}

// Round 8
// 1037.344 us; speedup vs baseline: 9.9204x; 1.4282x over previous
//
#include <hip/hip_runtime.h>
#include <hip/hip_bf16.h>

#define NB 8
#define LSEQ 2048
#define DM 768
#define DI 1536
#define DS 16
#define NT (NB*LSEQ)   // 16384 tokens
#define NC 32          // scan chunks per sequence
#define CHL (LSEQ/NC)  // 64 tokens per chunk

typedef __hip_bfloat16 bf16;
typedef __bf16 bf16x8 __attribute__((ext_vector_type(8)));
typedef float  f32x4  __attribute__((ext_vector_type(4)));

__device__ __forceinline__ float b2f(bf16 v){ return __bfloat162float(v); }
__device__ __forceinline__ bf16  f2b(float v){ return __float2bfloat16(v); }
__device__ __forceinline__ float silu(float v){ return v/(1.f+__expf(-v)); }

// ---------------- LN stats: one wave per token ----------------
__global__ void ln_stats(const float* __restrict__ x, float* __restrict__ stats){
  int wv = threadIdx.x>>6, ln = threadIdx.x&63;
  int t = blockIdx.x*4 + wv;
  const float* xr = x + (size_t)t*DM;
  float s=0.f, s2=0.f;
  for (int i=ln;i<DM;i+=64){ float v=xr[i]; s+=v; s2+=v*v; }
  #pragma unroll
  for (int o=32;o>0;o>>=1){ s+=__shfl_down(s,o); s2+=__shfl_down(s2,o); }
  if (ln==0){
    float mean = s/(float)DM;
    stats[2*t]   = mean;
    stats[2*t+1] = rsqrtf(s2/(float)DM - mean*mean + 1e-5f);
  }
}

// ---------------- in_proj MFMA GEMM with LN fused ----------------
__global__ __launch_bounds__(256) void gemm_in_mfma(
    const float* __restrict__ x, const float* __restrict__ stats,
    const float* __restrict__ g, const float* __restrict__ bb,
    const float* __restrict__ W,
    bf16* __restrict__ xb, bf16* __restrict__ z){
  __shared__ __align__(16) bf16 sA[128][40];
  __shared__ __align__(16) bf16 sW[128][40];
  int tid = threadIdx.x;
  int m0 = blockIdx.y*128, n0 = blockIdx.x*128;
  int sr = tid>>1, sc = (tid&1)*16;
  int arow = m0 + sr;
  float mean = stats[2*arow], rstd = stats[2*arow+1];
  int wave = tid>>6, lane = tid&63;
  int wm = (wave>>1)*64, wn = (wave&1)*64;
  int lr = lane&15, kq = lane>>4;
  f32x4 acc[4][4];
  #pragma unroll
  for (int i=0;i<4;i++)
    #pragma unroll
    for (int j=0;j<4;j++) acc[i][j] = (f32x4){0.f,0.f,0.f,0.f};

  for (int k0=0;k0<DM;k0+=32){
    const float4* xs   = (const float4*)(x  + (size_t)arow*DM + k0 + sc);
    const float4* gs   = (const float4*)(g  + k0 + sc);
    const float4* bs   = (const float4*)(bb + k0 + sc);
    const float4* wsrc = (const float4*)(W  + (size_t)(n0+sr)*DM + k0 + sc);
    bf16 ta[16] __attribute__((aligned(16)));
    bf16 tw[16] __attribute__((aligned(16)));
    #pragma unroll
    for (int u=0;u<4;u++){
      float4 xv=xs[u], gv=gs[u], bv=bs[u], wv=wsrc[u];
      ta[4*u+0]=f2b((xv.x-mean)*rstd*gv.x+bv.x);
      ta[4*u+1]=f2b((xv.y-mean)*rstd*gv.y+bv.y);
      ta[4*u+2]=f2b((xv.z-mean)*rstd*gv.z+bv.z);
      ta[4*u+3]=f2b((xv.w-mean)*rstd*gv.w+bv.w);
      tw[4*u+0]=f2b(wv.x); tw[4*u+1]=f2b(wv.y);
      tw[4*u+2]=f2b(wv.z); tw[4*u+3]=f2b(wv.w);
    }
    *(uint4*)&sA[sr][sc]   = ((uint4*)ta)[0];
    *(uint4*)&sA[sr][sc+8] = ((uint4*)ta)[1];
    *(uint4*)&sW[sr][sc]   = ((uint4*)tw)[0];
    *(uint4*)&sW[sr][sc+8] = ((uint4*)tw)[1];
    __syncthreads();
    bf16x8 af[4], bfr[4];
    #pragma unroll
    for (int i=0;i<4;i++) af[i]  = *(const bf16x8*)&sA[wm+i*16+lr][kq*8];
    #pragma unroll
    for (int j=0;j<4;j++) bfr[j] = *(const bf16x8*)&sW[wn+j*16+lr][kq*8];
    #pragma unroll
    for (int i=0;i<4;i++)
      #pragma unroll
      for (int j=0;j<4;j++)
        acc[i][j] = __builtin_amdgcn_mfma_f32_16x16x32_bf16(af[i], bfr[j], acc[i][j], 0,0,0);
    __syncthreads();
  }
  #pragma unroll
  for (int i=0;i<4;i++){
    #pragma unroll
    for (int j=0;j<4;j++){
      int colg = n0 + wn + j*16 + lr;
      #pragma unroll
      for (int r=0;r<4;r++){
        int rowg = m0 + wm + i*16 + kq*4 + r;
        float v = acc[i][j][r];
        if (colg < DI) xb[(size_t)rowg*DI + colg]      = f2b(v);
        else           z [(size_t)rowg*DI + colg - DI] = f2b(v);
      }
    }
  }
}

// ---------------- out_proj MFMA GEMM + residual, fp32 out ----------------
__global__ __launch_bounds__(256) void gemm_out_mfma(
    const bf16* __restrict__ ys, const float* __restrict__ W,
    const float* __restrict__ xres, float* __restrict__ out){
  __shared__ __align__(16) bf16 sA[128][40];
  __shared__ __align__(16) bf16 sW[128][40];
  int tid = threadIdx.x;
  int m0 = blockIdx.y*128, n0 = blockIdx.x*128;
  int sr = tid>>1, sc = (tid&1)*16;
  int wave = tid>>6, lane = tid&63;
  int wm = (wave>>1)*64, wn = (wave&1)*64;
  int lr = lane&15, kq = lane>>4;
  f32x4 acc[4][4];
  #pragma unroll
  for (int i=0;i<4;i++)
    #pragma unroll
    for (int j=0;j<4;j++) acc[i][j] = (f32x4){0.f,0.f,0.f,0.f};

  for (int k0=0;k0<DI;k0+=32){
    const uint4* asrc = (const uint4*)(ys + (size_t)(m0+sr)*DI + k0 + sc);
    uint4 a0 = asrc[0], a1 = asrc[1];
    const float4* wsrc = (const float4*)(W + (size_t)(n0+sr)*DI + k0 + sc);
    bf16 tw[16] __attribute__((aligned(16)));
    #pragma unroll
    for (int u=0;u<4;u++){
      float4 wv=wsrc[u];
      tw[4*u+0]=f2b(wv.x); tw[4*u+1]=f2b(wv.y);
      tw[4*u+2]=f2b(wv.z); tw[4*u+3]=f2b(wv.w);
    }
    *(uint4*)&sA[sr][sc]   = a0;
    *(uint4*)&sA[sr][sc+8] = a1;
    *(uint4*)&sW[sr][sc]   = ((uint4*)tw)[0];
    *(uint4*)&sW[sr][sc+8] = ((uint4*)tw)[1];
    __syncthreads();
    bf16x8 af[4], bfr[4];
    #pragma unroll
    for (int i=0;i<4;i++) af[i]  = *(const bf16x8*)&sA[wm+i*16+lr][kq*8];
    #pragma unroll
    for (int j=0;j<4;j++) bfr[j] = *(const bf16x8*)&sW[wn+j*16+lr][kq*8];
    #pragma unroll
    for (int i=0;i<4;i++)
      #pragma unroll
      for (int j=0;j<4;j++)
        acc[i][j] = __builtin_amdgcn_mfma_f32_16x16x32_bf16(af[i], bfr[j], acc[i][j], 0,0,0);
    __syncthreads();
  }
  #pragma unroll
  for (int i=0;i<4;i++){
    #pragma unroll
    for (int j=0;j<4;j++){
      int colg = n0 + wn + j*16 + lr;
      #pragma unroll
      for (int r=0;r<4;r++){
        int rowg = m0 + wm + i*16 + kq*4 + r;
        out[(size_t)rowg*DM + colg] = acc[i][j][r] + xres[(size_t)rowg*DM + colg];
      }
    }
  }
}

// ---------------- conv + SiLU: xbc = silu(depthwise_conv(xb)), bf16 out ----------------
// one thread per (token, 8-channel group)
__global__ __launch_bounds__(256) void conv_silu(
    const bf16* __restrict__ xb, const float* __restrict__ cw,
    const float* __restrict__ cb, bf16* __restrict__ xbc){
  int idx = blockIdx.x*256 + threadIdx.x;
  const int GPD = DI/8;           // 192 groups per token
  int gd = idx % GPD;
  int t  = idx / GPD;
  int l  = t % LSEQ;
  int d0 = gd*8;
  float v[4][8];
  #pragma unroll
  for (int r=0;r<4;r++){
    int off = 3-r;
    if (l >= off){
      uint4 raw = *(const uint4*)(xb + (size_t)(t-off)*DI + d0);
      const bf16* p = (const bf16*)&raw;
      #pragma unroll
      for (int j=0;j<8;j++) v[r][j] = b2f(p[j]);
    } else {
      #pragma unroll
      for (int j=0;j<8;j++) v[r][j] = 0.f;
    }
  }
  bf16 outv[8] __attribute__((aligned(16)));
  #pragma unroll
  for (int j=0;j<8;j++){
    int d = d0+j;
    float acc = cb[d] + v[0][j]*cw[d*4+0] + v[1][j]*cw[d*4+1]
                      + v[2][j]*cw[d*4+2] + v[3][j]*cw[d*4+3];
    outv[j] = f2b(silu(acc));
  }
  *(uint4*)(xbc + (size_t)t*DI + d0) = *(uint4*)outv;
}

// ---------------- x_proj MFMA GEMM: xp[NT,33] = xbc @ Wx[33,1536]^T ----------------
// grid (NT/128), block 256 (4 waves; wave w = rows w*32..w*32+31, cols 0..47)
__global__ __launch_bounds__(256) void xproj_mfma(
    const bf16* __restrict__ xbc, const float* __restrict__ Wx,
    float* __restrict__ xp){
  __shared__ __align__(16) bf16 sA[128][40];
  __shared__ __align__(16) bf16 sW[48][40];
  int tid = threadIdx.x;
  int m0 = blockIdx.x*128;
  int sr = tid>>1, sc = (tid&1)*16;
  int wave = tid>>6, lane = tid&63;
  int wm = wave*32;
  int lr = lane&15, kq = lane>>4;
  f32x4 acc[2][3];
  #pragma unroll
  for (int i=0;i<2;i++)
    #pragma unroll
    for (int j=0;j<3;j++) acc[i][j] = (f32x4){0.f,0.f,0.f,0.f};

  for (int k0=0;k0<DI;k0+=32){
    const uint4* asrc = (const uint4*)(xbc + (size_t)(m0+sr)*DI + k0 + sc);
    uint4 a0 = asrc[0], a1 = asrc[1];
    *(uint4*)&sA[sr][sc]   = a0;
    *(uint4*)&sA[sr][sc+8] = a1;
    if (tid < 96){
      int wr = tid>>1, wc = (tid&1)*16;
      bf16 tw[16] __attribute__((aligned(16)));
      if (wr < 33){
        const float4* wsrc = (const float4*)(Wx + (size_t)wr*DI + k0 + wc);
        #pragma unroll
        for (int u=0;u<4;u++){
          float4 wv=wsrc[u];
          tw[4*u+0]=f2b(wv.x); tw[4*u+1]=f2b(wv.y);
          tw[4*u+2]=f2b(wv.z); tw[4*u+3]=f2b(wv.w);
        }
      } else {
        #pragma unroll
        for (int u=0;u<16;u++) tw[u]=f2b(0.f);
      }
      *(uint4*)&sW[wr][wc]   = ((uint4*)tw)[0];
      *(uint4*)&sW[wr][wc+8] = ((uint4*)tw)[1];
    }
    __syncthreads();
    bf16x8 af[2], bfr[3];
    #pragma unroll
    for (int i=0;i<2;i++) af[i]  = *(const bf16x8*)&sA[wm+i*16+lr][kq*8];
    #pragma unroll
    for (int j=0;j<3;j++) bfr[j] = *(const bf16x8*)&sW[j*16+lr][kq*8];
    #pragma unroll
    for (int i=0;i<2;i++)
      #pragma unroll
      for (int j=0;j<3;j++)
        acc[i][j] = __builtin_amdgcn_mfma_f32_16x16x32_bf16(af[i], bfr[j], acc[i][j], 0,0,0);
    __syncthreads();
  }
  #pragma unroll
  for (int i=0;i<2;i++){
    #pragma unroll
    for (int j=0;j<3;j++){
      int col = j*16 + lr;
      if (col < 33){
        #pragma unroll
        for (int r=0;r<4;r++){
          int rowg = m0 + wm + i*16 + kq*4 + r;
          xp[(size_t)rowg*33 + col] = acc[i][j][r];
        }
      }
    }
  }
}

// ---------------- chunked selective scan (xbc materialized) ----------------
// grid (DI/64, NB, NC), block 64
__global__ __launch_bounds__(64) void scan_part1(
    const float* __restrict__ xp, const bf16* __restrict__ xbc,
    const float* __restrict__ dt_w, const float* __restrict__ dt_b,
    const float* __restrict__ A_log,
    float* __restrict__ Ssum, float* __restrict__ Hst){
  int tid = threadIdx.x;
  int d = blockIdx.x*64 + tid;
  int b = blockIdx.y, c = blockIdx.z;
  int l0 = c*CHL;
  size_t tbase = (size_t)b*LSEQ;
  __shared__ float sxp[CHL*33];
  __shared__ bf16  sxb[CHL][64];
  const float* xps = xp + (tbase + l0)*33;
  for (int i=tid;i<CHL*33;i+=64) sxp[i] = xps[i];
  const bf16* xbs = xbc + (tbase + l0)*DI + (size_t)blockIdx.x*64;
  for (int i=tid;i<CHL*16;i+=64){
    int t = i>>4, q = i&15;
    ((uint2*)&sxb[t][0])[q] = *(const uint2*)(xbs + (size_t)t*DI + q*4);
  }
  float A[DS];
  #pragma unroll
  for (int n=0;n<DS;n++) A[n] = -expf(A_log[(size_t)d*DS+n]);
  float dtw = dt_w[d], dtb = dt_b[d];
  float h[DS];
  #pragma unroll
  for (int n=0;n<DS;n++) h[n]=0.f;
  float S=0.f;
  __syncthreads();
  for (int lc=0;lc<CHL;lc++){
    float xt = b2f(sxb[lc][tid]);
    const float* sp = &sxp[lc*33];
    float dl = sp[0]*dtw + dtb;
    float delta = (dl > 20.f) ? dl : log1pf(__expf(dl));
    S += delta;
    float dx = delta*xt;
    #pragma unroll
    for (int n=0;n<DS;n++)
      h[n] = __expf(delta*A[n])*h[n] + dx*sp[1+n];
  }
  Ssum[((size_t)(b*NC+c))*DI + d] = S;
  #pragma unroll
  for (int n=0;n<DS;n++)
    Hst[((size_t)(b*NC+c)*DS+n)*DI + d] = h[n];
}

// grid (NB*DI/256), block 256: thread = (b,d); sequential over 32 chunks.
__global__ __launch_bounds__(256) void scan_part2(
    const float* __restrict__ A_log,
    const float* __restrict__ Ssum, float* __restrict__ Hst){
  int gid = blockIdx.x*256 + threadIdx.x;
  int b = gid / DI, d = gid % DI;
  float A[DS];
  #pragma unroll
  for (int n=0;n<DS;n++) A[n] = -expf(A_log[(size_t)d*DS+n]);
  float h[DS];
  #pragma unroll
  for (int n=0;n<DS;n++) h[n]=0.f;
  for (int c=0;c<NC;c++){
    float S = Ssum[((size_t)(b*NC+c))*DI + d];
    #pragma unroll
    for (int n=0;n<DS;n++){
      size_t hidx = ((size_t)(b*NC+c)*DS+n)*DI + d;
      float hl = Hst[hidx];
      Hst[hidx] = h[n];                       // true h_start for chunk c
      h[n] = __expf(S*A[n])*h[n] + hl;        // state after chunk c
    }
  }
}

// grid (DI/64, NB, NC), block 64. Replay from h_start; write gated y into z.
__global__ __launch_bounds__(64) void scan_part3(
    const float* __restrict__ xp, const bf16* __restrict__ xbc,
    bf16* __restrict__ z,
    const float* __restrict__ dt_w, const float* __restrict__ dt_b,
    const float* __restrict__ A_log, const float* __restrict__ Dp,
    const float* __restrict__ Hst){
  int tid = threadIdx.x;
  int d = blockIdx.x*64 + tid;
  int b = blockIdx.y, c = blockIdx.z;
  int l0 = c*CHL;
  size_t tbase = (size_t)b*LSEQ;
  __shared__ float sxp[CHL*33];
  __shared__ bf16  sxb[CHL][64];
  const float* xps = xp + (tbase + l0)*33;
  for (int i=tid;i<CHL*33;i+=64) sxp[i] = xps[i];
  const bf16* xbs = xbc + (tbase + l0)*DI + (size_t)blockIdx.x*64;
  for (int i=tid;i<CHL*16;i+=64){
    int t = i>>4, q = i&15;
    ((uint2*)&sxb[t][0])[q] = *(const uint2*)(xbs + (size_t)t*DI + q*4);
  }
  float A[DS];
  #pragma unroll
  for (int n=0;n<DS;n++) A[n] = -expf(A_log[(size_t)d*DS+n]);
  float dtw = dt_w[d], dtb = dt_b[d], Dd = Dp[d];
  float h[DS];
  #pragma unroll
  for (int n=0;n<DS;n++) h[n] = Hst[((size_t)(b*NC+c)*DS+n)*DI + d];
  __syncthreads();
  for (int lc=0;lc<CHL;lc++){
    size_t t = tbase + l0 + lc;
    float zv = b2f(z[t*DI + d]);
    float xt = b2f(sxb[lc][tid]);
    const float* sp = &sxp[lc*33];
    float dl = sp[0]*dtw + dtb;
    float delta = (dl > 20.f) ? dl : log1pf(__expf(dl));
    float dx = delta*xt;
    float y=0.f;
    #pragma unroll
    for (int n=0;n<DS;n++){
      h[n] = __expf(delta*A[n])*h[n] + dx*sp[1+n];
      y += h[n]*sp[1+DS+n];
    }
    y += Dd*xt;
    z[t*DI + d] = f2b(y*silu(zv));
  }
}

extern "C" void kernel_launch(void* const* d_in, const int* in_sizes, int n_in,
                              void* d_out, int out_size, void* d_ws, size_t ws_size,
                              hipStream_t stream) {
  const float* x        = (const float*)d_in[0];
  const float* ln_g     = (const float*)d_in[1];
  const float* ln_b     = (const float*)d_in[2];
  const float* in_w     = (const float*)d_in[3];
  const float* conv_w   = (const float*)d_in[4];
  const float* conv_b   = (const float*)d_in[5];
  const float* xproj_w  = (const float*)d_in[6];
  const float* dt_w     = (const float*)d_in[7];
  const float* dt_b     = (const float*)d_in[8];
  const float* A_log    = (const float*)d_in[9];
  const float* Dp       = (const float*)d_in[10];
  const float* out_w    = (const float*)d_in[11];
  float* out = (float*)d_out;

  // workspace layout (~103 MB, proven mapped):
  float* stats = (float*)d_ws;                         // NT*2 fp32
  float* xp    = stats + (size_t)NT*2;                 // NT*33 fp32
  bf16*  xbuf  = (bf16*)(xp + (size_t)NT*(2*DS+1));    // NT*DI bf16 (raw xb; dead after conv_silu)
  bf16*  zbuf  = xbuf + (size_t)NT*DI;                 // NT*DI bf16 (z -> gated ys)

  // xbc (bf16 NT*DI = 50.33 MB) lives in d_out until gemm_out overwrites it
  bf16* xbc = (bf16*)d_out;
  // scan state scratch reuses dead xbuf region (26.8 MB < 50.3 MB)
  float* Ssum = (float*)xbuf;                          // NB*NC*DI
  float* Hst  = Ssum + (size_t)NB*NC*DI;               // NB*NC*DS*DI

  ln_stats<<<NT/4, 256, 0, stream>>>(x, stats);

  gemm_in_mfma<<<dim3(2*DI/128, NT/128), 256, 0, stream>>>(
      x, stats, ln_g, ln_b, in_w, xbuf, zbuf);

  conv_silu<<<(NT*(DI/8))/256, 256, 0, stream>>>(xbuf, conv_w, conv_b, xbc);

  xproj_mfma<<<NT/128, 256, 0, stream>>>(xbc, xproj_w, xp);

  scan_part1<<<dim3(DI/64, NB, NC), 64, 0, stream>>>(
      xp, xbc, dt_w, dt_b, A_log, Ssum, Hst);

  scan_part2<<<NB*DI/256, 256, 0, stream>>>(A_log, Ssum, Hst);

  scan_part3<<<dim3(DI/64, NB, NC), 64, 0, stream>>>(
      xp, xbc, zbuf, dt_w, dt_b, A_log, Dp, Hst);

  gemm_out_mfma<<<dim3(DM/128, NT/128), 256, 0, stream>>>(zbuf, out_w, x, out);
}